// Round 8
// baseline (577.947 us; speedup 1.0000x reference)
//
#include <hip/hip_runtime.h>

// x:(1,64,64,768) -> n=4096 tokens, DIM=768, 12 heads x 64 dim
#define NTOK 4096
#define DIMD 768
#define NHD  12
#define HDD  64
#define DK   800   // extended K: 768 x | 4 lora-q | 4 lora-v | 24 zero

typedef float  f32x2  __attribute__((ext_vector_type(2)));
typedef float  f32x4  __attribute__((ext_vector_type(4)));
typedef float  f32x16 __attribute__((ext_vector_type(16)));
typedef short  s16x8  __attribute__((ext_vector_type(8)));

#define MFMA16(a, b, c) __builtin_amdgcn_mfma_f32_16x16x32_bf16(a, b, c, 0, 0, 0)
#define MFMA32(a, b, c) __builtin_amdgcn_mfma_f32_32x32x16_bf16(a, b, c, 0, 0, 0)

#if __has_builtin(__builtin_amdgcn_exp2f)
#define EXP2(x) __builtin_amdgcn_exp2f(x)
#else
#define EXP2(x) exp2f(x)
#endif

__device__ inline short f2b(float f) {  // fp32 -> bf16 RNE
  unsigned u = __float_as_uint(f);
  u += 0x7FFFu + ((u >> 16) & 1u);
  return (short)(u >> 16);
}
__device__ inline float b2f(short s) {
  return __uint_as_float(((unsigned)(unsigned short)s) << 16);
}
__device__ inline void gl_lds16(const short* g, short* l) {
  __builtin_amdgcn_global_load_lds(
      (const __attribute__((address_space(1))) unsigned int*)g,
      (__attribute__((address_space(3))) unsigned int*)l, 16, 0, 0);
}

// ws layout (float units):
//   xe    @0         bf16 [4096][800]
//   we    @1638400   bf16 [2304][800]
//   wpb   @2560000   bf16 [768][768]
//   qkvb  @2854912   bf16 [3][12][4096][64]  (V third unused)
//   vtb   @7573504   bf16 [12][64][4096]  (keys pi-permuted within 16-groups)
//   attnb @9146368   bf16 [4096][768]

// ---------------------------------------------------------------------------
// Kernel A: build extended weights we[2304][800] and wpb[768][768] (bf16)
__global__ __launch_bounds__(64)
void k_prep_w(const float* __restrict__ Wqkv, const float* __restrict__ Bq,
              const float* __restrict__ Bv, const float* __restrict__ Wp,
              short* __restrict__ we, short* __restrict__ wpb) {
  const int j = blockIdx.x;
  const int l = threadIdx.x;
  if (j < 2304) {
#pragma unroll
    for (int k = 0; k < 12; ++k)
      we[(size_t)j * DK + l + 64 * k] = f2b(Wqkv[(size_t)j * DIMD + l + 64 * k]);
    if (l < 32) {
      int c = 768 + l;
      short v = 0;
      if (l < 4) {
        if (j < 768) v = f2b(Bq[j * 4 + l]);
      } else if (l < 8) {
        if (j >= 1536) v = f2b(Bv[(j - 1536) * 4 + (l - 4)]);
      }
      we[(size_t)j * DK + c] = v;
    }
  } else {
    const int jr = j - 2304;
#pragma unroll
    for (int k = 0; k < 12; ++k)
      wpb[(size_t)jr * DIMD + l + 64 * k] =
          f2b(Wp[(size_t)jr * DIMD + l + 64 * k]);
  }
}

// ---------------------------------------------------------------------------
// Kernel B: build xe[4096][800] = [bf16(x) | 0.25*x@Aq^T | 0.25*x@Av^T | 0]
__global__ __launch_bounds__(64)
void k_prep_x(const float* __restrict__ x, const float* __restrict__ Aq,
              const float* __restrict__ Av, short* __restrict__ xe) {
  const int i = blockIdx.x;
  const int l = threadIdx.x;
  float xv[12];
#pragma unroll
  for (int k = 0; k < 12; ++k) xv[k] = x[(size_t)i * DIMD + l + 64 * k];
#pragma unroll
  for (int k = 0; k < 12; ++k)
    xe[(size_t)i * DK + l + 64 * k] = f2b(xv[k]);
  float a8[8];
#pragma unroll
  for (int o = 0; o < 8; ++o) {
    const float* A = (o < 4) ? (Aq + o * DIMD) : (Av + (o - 4) * DIMD);
    float acc = 0.f;
#pragma unroll
    for (int k = 0; k < 12; ++k) acc = fmaf(xv[k], A[l + 64 * k], acc);
#pragma unroll
    for (int off = 32; off; off >>= 1) acc += __shfl_xor(acc, off, 64);
    a8[o] = acc;
  }
  if (l < 32) {
    float v = 0.f;
#pragma unroll
    for (int o = 0; o < 8; ++o)
      if (l == o) v = 0.25f * a8[o];
    xe[(size_t)i * DK + 768 + l] = (l < 8) ? f2b(v) : (short)0;
  }
}

// ---------------------------------------------------------------------------
// Kernel 2: bf16 MFMA qkv GEMM over extended K=800 (LoRA folded in).
// BK=64 main loop (12 steps) + BK=32 tail, XOR-swizzled LDS, Cs aliased over
// As/Bs (33.3 KB LDS), XCD-aware swizzle. (unchanged)
__global__ __launch_bounds__(256)
void k_qkv(const short* __restrict__ xe, const short* __restrict__ we,
           const float* __restrict__ bqkv, short* __restrict__ qkvb,
           short* __restrict__ vtb) {
  const int d_ = blockIdx.y * 18 + blockIdx.x;
  const int lin = (d_ & 7) * 72 + (d_ >> 3);
  const int j0 = (lin % 18) * 128;
  const int i0 = (lin / 18) * 128;

  __shared__ __align__(16) short shm[16640];
  short* As = shm;
  short* Bs = shm + 8192;
  short* Cs = shm;

  const int t = threadIdx.x, lane = t & 63, w = t >> 6;
  const int l15 = lane & 15, quad = lane >> 4;
  const int wm = w >> 1, wn = w & 1;

  f32x4 acc[4][4];
#pragma unroll
  for (int a = 0; a < 4; ++a)
#pragma unroll
    for (int b = 0; b < 4; ++b) acc[a][b] = (f32x4){0.f, 0.f, 0.f, 0.f};

  for (int kk = 0; kk < 768; kk += 64) {
    __syncthreads();
#pragma unroll
    for (int rep = 0; rep < 4; ++rep) {
      int c = rep * 256 + w * 64 + lane;
      int row = c >> 3, u = (c & 7) ^ (row & 7);
      gl_lds16(xe + (size_t)(i0 + row) * DK + kk + u * 8,
               &As[(rep * 256 + w * 64) * 8]);
      gl_lds16(we + (size_t)(j0 + row) * DK + kk + u * 8,
               &Bs[(rep * 256 + w * 64) * 8]);
    }
    __syncthreads();
#pragma unroll
    for (int kh2 = 0; kh2 < 2; ++kh2) {
      s16x8 af[4], bf[4];
#pragma unroll
      for (int mt = 0; mt < 4; ++mt) {
        int row = wm * 64 + mt * 16 + l15;
        af[mt] = *(const s16x8*)&As[row * 64 +
                                    (((kh2 * 4 + quad) ^ (l15 & 7)) * 8)];
      }
#pragma unroll
      for (int nt = 0; nt < 4; ++nt) {
        int row = wn * 64 + nt * 16 + l15;
        bf[nt] = *(const s16x8*)&Bs[row * 64 +
                                    (((kh2 * 4 + quad) ^ (l15 & 7)) * 8)];
      }
#pragma unroll
      for (int mt = 0; mt < 4; ++mt)
#pragma unroll
        for (int nt = 0; nt < 4; ++nt)
          acc[mt][nt] = MFMA16(af[mt], bf[nt], acc[mt][nt]);
    }
  }

  __syncthreads();
#pragma unroll
  for (int rep = 0; rep < 2; ++rep) {
    int c = rep * 256 + w * 64 + lane;
    gl_lds16(xe + (size_t)(i0 + (c >> 2)) * DK + 768 + (c & 3) * 8,
             &As[(rep * 256 + w * 64) * 8]);
    gl_lds16(we + (size_t)(j0 + (c >> 2)) * DK + 768 + (c & 3) * 8,
             &Bs[(rep * 256 + w * 64) * 8]);
  }
  __syncthreads();
  {
    s16x8 af[4], bf[4];
#pragma unroll
    for (int mt = 0; mt < 4; ++mt)
      af[mt] = *(const s16x8*)&As[(wm * 64 + mt * 16 + l15) * 32 + quad * 8];
#pragma unroll
    for (int nt = 0; nt < 4; ++nt)
      bf[nt] = *(const s16x8*)&Bs[(wn * 64 + nt * 16 + l15) * 32 + quad * 8];
#pragma unroll
    for (int mt = 0; mt < 4; ++mt)
#pragma unroll
      for (int nt = 0; nt < 4; ++nt)
        acc[mt][nt] = MFMA16(af[mt], bf[nt], acc[mt][nt]);
  }
  __syncthreads();

  const int which = j0 / DIMD;
  float bj[4];
#pragma unroll
  for (int nt = 0; nt < 4; ++nt) bj[nt] = bqkv[j0 + wn * 64 + nt * 16 + l15];

#pragma unroll
  for (int mt = 0; mt < 4; ++mt)
#pragma unroll
    for (int r = 0; r < 4; ++r) {
      const int row = wm * 64 + mt * 16 + quad * 4 + r;
#pragma unroll
      for (int nt = 0; nt < 4; ++nt) {
        const int col = wn * 64 + nt * 16 + l15;
        Cs[row * 130 + col] = f2b(acc[mt][nt][r] + bj[nt]);
      }
    }
  __syncthreads();
  const int base_head = (j0 - which * DIMD) >> 6;
  if (which != 2) {
#pragma unroll
    for (int rp = 0; rp < 8; ++rp) {
      int f = t + 256 * rp;
      int row = f >> 4, ch = f & 15;
      int head = base_head + (ch >> 3);
      int ddb = (ch & 7) * 8;
      s16x8 v = *(const s16x8*)&Cs[row * 130 + ch * 8];
      *(s16x8*)&qkvb[(((size_t)which * NHD + head) * NTOK + i0 + row) * HDD + ddb] = v;
    }
  } else {
#pragma unroll
    for (int rp = 0; rp < 8; ++rp) {
      int f = t + 256 * rp;
      int dcol = f >> 4, n8 = (f & 15) * 8;
      unsigned wds[4];
#pragma unroll
      for (int m = 0; m < 4; ++m) {
        int s0 = n8 + 2 * m, s1 = s0 + 1;
        int sr0 = (s0 & 0x70) | ((((s0 >> 2) & 3) == 1 ? 2 : ((s0 >> 2) & 3) == 2 ? 1 : ((s0 >> 2) & 3)) << 2) | (s0 & 3);
        int sr1 = (s1 & 0x70) | ((((s1 >> 2) & 3) == 1 ? 2 : ((s1 >> 2) & 3) == 2 ? 1 : ((s1 >> 2) & 3)) << 2) | (s1 & 3);
        unsigned lo = (unsigned short)Cs[sr0 * 130 + dcol];
        unsigned hi = (unsigned short)Cs[sr1 * 130 + dcol];
        wds[m] = lo | (hi << 16);
      }
      short* dst = vtb + ((size_t)(base_head * 64) + dcol) * NTOK + i0 + n8;
      *(int4*)dst = *(int4*)&wds[0];
    }
  }
}

// ---------------------------------------------------------------------------
// Kernel 4: 8-wave split-KV flash attention. 768 blocks x 512 threads.
// Wave group g = w>>2 owns keys [g*2048, g*2048+2048): 32 tiles of 64 keys.
// Per-wave main-loop chain is HALF the 4-wave version; prologue (RW/M/bw2/
// RH staging, Q frags) is shared and paid once. Cross-group merge in the
// epilogue via LDS (no partials, no combine kernel). Single-buffered K and
// V per group (LDS 42.75 KB -> 3 blocks/CU); __launch_bounds__(512,6)
// forces VGPR<=85 so 24 waves/CU (6/SIMD) are co-resident = demand.
// bw2 kept as packed bf16 pairs (8 u32) to fit the register budget.
// Per-group LDS shorts @ G=g*10240: K@G, V@G+4096, bHb@G+8192 (2048).
__global__ __launch_bounds__(512, 6)
void k_attn7(const short* __restrict__ qkvb, const short* __restrict__ vtb,
             const float* __restrict__ relh, const float* __restrict__ relw,
             short* __restrict__ attnb) {
  // T1: bijective XCD swizzle (768 = 8 XCDs x 96).
  const int d_ = blockIdx.y * 64 + blockIdx.x;
  const int lin = (d_ & 7) * 96 + (d_ >> 3);
  const int head = lin >> 6;
  const int hq = lin & 63;
  const int n0 = hq * 64;

  __shared__ short sm[21376];          // 42752 B
  short* smb = sm;

  const short* qg  = qkvb + (size_t)(0 * NHD + head) * NTOK * HDD;
  const short* kg  = qkvb + (size_t)(1 * NHD + head) * NTOK * HDD;
  const short* vtg = vtb + (size_t)head * HDD * NTOK;

  const int t = threadIdx.x;
  const int w = t >> 6, lane = t & 63;
  const int l31 = lane & 31, h = lane >> 5;
  const int g = w >> 2, wg = w & 3;
  const int kh = (w >> 1) & 1, qh = w & 1;
  const int q = qh * 32 + l31;
  const int G = g * 10240;

  // DMA source offsets (R2-verified slot map, wg in place of w)
  const int rowp = lane >> 1;
  const int cw = (wg * 2 + (lane & 1)) * 8;
  const short* kg_ = kg + (size_t)g * 2048 * HDD;      // + kt*4096 + koff
  const short* vg_ = vtg + g * 2048;                    // + kt*64 + voff
  const int koff = rowp * HDD + cw;
  const int voff = rowp * NTOK + cw;

  // Q B-fragments (persist; duplicated across g and kh, as before)
  s16x8 qb[4];
#pragma unroll
  for (int s = 0; s < 4; ++s)
    qb[s] = *(const s16x8*)&qg[(size_t)(n0 + q) * HDD + s * 16 + 8 * h];

  // ---- prologue: RW -> overlay (512 threads, 2 passes) ----
#pragma unroll
  for (int rp = 0; rp < 2; ++rp) {
    int f = t + 512 * rp;
    int d = f >> 3, c = (f & 7) * 8;
    float4 v0 = make_float4(0, 0, 0, 0), v1 = v0;
    if (d < 127) {
      const float* s_ = relw + (size_t)d * HDD + c;
      v0 = *(const float4*)s_; v1 = *(const float4*)(s_ + 4);
    }
    short4 b0, b1;
    b0.x = f2b(v0.x); b0.y = f2b(v0.y); b0.z = f2b(v0.z); b0.w = f2b(v0.w);
    b1.x = f2b(v1.x); b1.y = f2b(v1.y); b1.z = f2b(v1.z); b1.w = f2b(v1.w);
    *(short4*)&smb[d * 72 + c] = b0;
    *(short4*)&smb[d * 72 + c + 4] = b1;
  }
  __syncthreads();

  // M^T = RW @ Q^T: wave (g,kh) computes rowblock r = g*2+kh (one mc each)
  {
    const int r = g * 2 + kh;
    f32x16 mc = (f32x16)(0.f);
#pragma unroll
    for (int s = 0; s < 4; ++s) {
      s16x8 a = *(const s16x8*)&smb[(r * 32 + l31) * 72 + s * 16 + 8 * h];
      mc = MFMA32(a, qb[s], mc);
    }
    __syncthreads();
#pragma unroll
    for (int reg = 0; reg < 16; ++reg) {
      int dl = (reg & 3) + 8 * (reg >> 2) + 4 * h;
      smb[(r * 32 + dl) * 64 + q] = f2b(mc[reg] * 1.44269504f);
    }
  }
  __syncthreads();

  // bw2 extraction, packed bf16 pairs (saves 8 VGPRs)
  unsigned bw2p[8];
#pragma unroll
  for (int i = 0; i < 8; ++i) {
    unsigned sb[2];
#pragma unroll
    for (int p = 0; p < 2; ++p) {
      int reg = 2 * i + p;
      int kl64 = kh * 32 + (reg & 3) + 8 * (reg >> 2) + 4 * h;
      int dneed = q - kl64 + 63;  // [0,126]
      sb[p] = (unsigned short)smb[dneed * 64 + q];
    }
    bw2p[i] = sb[0] | (sb[1] << 16);
  }
  __syncthreads();

  // RH -> overlay (single pass, 64 rows)
  {
    int kt = t >> 3, c = (t & 7) * 8;
    const float* s_ = relh + (size_t)(hq + 63 - kt) * HDD + c;
    float4 v0 = *(const float4*)s_, v1 = *(const float4*)(s_ + 4);
    short4 b0, b1;
    b0.x = f2b(v0.x); b0.y = f2b(v0.y); b0.z = f2b(v0.z); b0.w = f2b(v0.w);
    b1.x = f2b(v1.x); b1.y = f2b(v1.y); b1.z = f2b(v1.z); b1.w = f2b(v1.w);
    *(short4*)&smb[kt * 72 + c] = b0;
    *(short4*)&smb[kt * 72 + c + 4] = b1;
  }
  __syncthreads();

  // bH^T for this group's 32 tiles -> bHb_g @ G+8192 (kh waves duplicate)
  {
    f32x16 hc = (f32x16)(0.f);
#pragma unroll
    for (int s = 0; s < 4; ++s) {
      s16x8 a = *(const s16x8*)&smb[(g * 32 + l31) * 72 + s * 16 + 8 * h];
      hc = MFMA32(a, qb[s], hc);
    }
    __syncthreads();  // RH reads done before V buffer (G+4096) overwrites it
#pragma unroll
    for (int reg = 0; reg < 16; ++reg) {
      int ktl = (reg & 3) + 8 * (reg >> 2) + 4 * h;
      smb[G + 8192 + ktl * 64 + q] = f2b(hc[reg] * 1.44269504f);
    }
  }
  __syncthreads();

  // read bases (fold into one VGPR each; ds offsets are immediates)
  const int sbase = G + kh * 2048 + l31 * 16 + h * 8;          // K frags
  const int vbase = G + 4096 + kh * 1024 + l31 * 16 + h * 8;   // V frags

  float ps0 = 0.f, ps1 = 0.f;
  f32x16 oc0 = (f32x16)(0.f), oc1 = (f32x16)(0.f);

  for (int kt = 0; kt < 32; ++kt) {
    __syncthreads();   // all waves done reading K/V(kt-1): buffers free
    gl_lds16(kg_ + (size_t)kt * 4096 + koff, smb + G + wg * 512);
    gl_lds16(kg_ + (size_t)kt * 4096 + 2048 + koff, smb + G + 2048 + wg * 512);
    gl_lds16(vg_ + (size_t)kt * 64 + voff, smb + G + 4096 + wg * 512);
    gl_lds16(vg_ + (size_t)kt * 64 + (size_t)32 * NTOK + voff,
             smb + G + 4096 + 2048 + wg * 512);
    float bhl2 = b2f(smb[G + 8192 + kt * 64 + q]);   // read-only, overlaps DMA
    __syncthreads();   // vmcnt(0) drain + barrier: K/V(kt) published

    f32x16 sc_ = (f32x16)(0.f);
#pragma unroll
    for (int s = 0; s < 4; ++s) {
      s16x8 a = *(const s16x8*)&smb[sbase + s * 512];
      sc_ = MFMA32(a, qb[s], sc_);
    }
    unsigned pk[8];
#pragma unroll
    for (int i = 0; i < 8; ++i) {
      float f0 = __uint_as_float(bw2p[i] << 16);
      float f1 = __uint_as_float(bw2p[i] & 0xFFFF0000u);
      float r0 = sc_[2 * i] * 0.18033688f + (f0 + bhl2);
      float r1 = sc_[2 * i + 1] * 0.18033688f + (f1 + bhl2);
      float e0 = EXP2(r0);
      float e1 = EXP2(r1);
      ps0 += e0; ps1 += e1;
      pk[i] = __builtin_amdgcn_perm(__float_as_uint(e1),
                                    __float_as_uint(e0), 0x07060302u);
    }
#pragma unroll
    for (int s2i = 0; s2i < 2; ++s2i) {
      union { unsigned u[4]; s16x8 v; } B;
      B.u[0] = pk[4 * s2i + 0]; B.u[1] = pk[4 * s2i + 1];
      B.u[2] = pk[4 * s2i + 2]; B.u[3] = pk[4 * s2i + 3];
      s16x8 a0 = *(const s16x8*)&smb[vbase + s2i * 512];
      s16x8 a1 = *(const s16x8*)&smb[vbase + s2i * 512 + 2048];
      oc0 = MFMA32(a0, B.v, oc0);
      oc1 = MFMA32(a1, B.v, oc1);
    }
  }

  // ---- epilogue: merge kh halves per group, then groups, then store ----
  __syncthreads();
  float ps = ps0 + ps1;
  ps += __shfl_xor(ps, 32, 64);
  float* fbuf = (float*)smb;
  float* obuf0 = fbuf;                 // [64][66]
  float* psb0  = fbuf + 4224;          // [64]
  float* obuf1 = fbuf + 4288;          // [64][66]
  float* psb1  = fbuf + 8512;          // [64]
  short* tbuf  = smb + 17152;          // [64][66] shorts
  float* obufg = g ? obuf1 : obuf0;
  float* psbg  = g ? psb1 : psb0;
  if (kh == 1) {                       // stage A: kh1 waves seed obuf_g
#pragma unroll
    for (int reg = 0; reg < 16; ++reg) {
      int dl = (reg & 3) + 8 * (reg >> 2) + 4 * h;
      obufg[dl * 66 + q] = oc0[reg];
      obufg[(32 + dl) * 66 + q] = oc1[reg];
    }
    if (lane < 32) psbg[q] = ps;
  }
  __syncthreads();
  if (g == 1 && kh == 0) {             // stage B: finish group-1 totals
#pragma unroll
    for (int reg = 0; reg < 16; ++reg) {
      int dl = (reg & 3) + 8 * (reg >> 2) + 4 * h;
      obuf1[dl * 66 + q] += oc0[reg];
      obuf1[(32 + dl) * 66 + q] += oc1[reg];
    }
    if (lane < 32) psb1[q] += ps;
  }
  __syncthreads();
  if (g == 0 && kh == 0) {             // stage C: final merge + normalize
    float inv = 1.f / (ps + psb0[q] + psb1[q]);
#pragma unroll
    for (int reg = 0; reg < 16; ++reg) {
      int dl = (reg & 3) + 8 * (reg >> 2) + 4 * h;
      tbuf[dl * 66 + q] =
          f2b((oc0[reg] + obuf0[dl * 66 + q] + obuf1[dl * 66 + q]) * inv);
      tbuf[(32 + dl) * 66 + q] =
          f2b((oc1[reg] + obuf0[(32 + dl) * 66 + q] + obuf1[(32 + dl) * 66 + q]) * inv);
    }
  }
  __syncthreads();
  if (t < 256) {
    int qq = t >> 2, seg = t & 3;
    unsigned wds[8];
#pragma unroll
    for (int m = 0; m < 8; ++m) {
      unsigned lo = (unsigned short)tbuf[(seg * 16 + 2 * m) * 66 + qq];
      unsigned hi = (unsigned short)tbuf[(seg * 16 + 2 * m + 1) * 66 + qq];
      wds[m] = lo | (hi << 16);
    }
    short* dst = attnb + (size_t)(n0 + qq) * DIMD + head * 64 + seg * 16;
    *(int4*)dst = *(int4*)&wds[0];
    *(int4*)(dst + 8) = *(int4*)&wds[4];
  }
}

// ---------------------------------------------------------------------------
// Kernel 5: bf16 MFMA proj: out = attn @ Wp^T + bp (fp32 out)
__global__ __launch_bounds__(256)
void k_proj(const short* __restrict__ ab, const short* __restrict__ wpb,
            const float* __restrict__ bp, float* __restrict__ out) {
  const int d_ = blockIdx.y * 12 + blockIdx.x;
  const int lin = (d_ & 7) * 48 + (d_ >> 3);
  const int j0 = (lin % 12) * 64;
  const int i0 = (lin / 12) * 128;
  __shared__ short As[128 * 32];
  __shared__ short Bs[64 * 32];
  const int t = threadIdx.x, lane = t & 63, w = t >> 6;
  const int l15 = lane & 15, quad = lane >> 4;
  const int wm = w >> 1, wn = w & 1;

  f32x4 acc[4][2];
#pragma unroll
  for (int a = 0; a < 4; ++a)
#pragma unroll
    for (int b = 0; b < 2; ++b) acc[a][b] = (f32x4){0.f, 0.f, 0.f, 0.f};

  for (int kk = 0; kk < DIMD; kk += 32) {
    __syncthreads();
#pragma unroll
    for (int rep = 0; rep < 2; ++rep) {
      int c = rep * 256 + w * 64 + lane;
      gl_lds16(ab + (size_t)(i0 + (c >> 2)) * DIMD + kk + (c & 3) * 8,
               &As[(rep * 256 + w * 64) * 8]);
    }
    {
      gl_lds16(wpb + (size_t)(j0 + ((w * 64 + lane) >> 2)) * DIMD + kk +
                   ((w * 64 + lane) & 3) * 8,
               &Bs[(w * 64) * 8]);
    }
    __syncthreads();
    s16x8 af[4], bf[2];
#pragma unroll
    for (int mt = 0; mt < 4; ++mt)
      af[mt] = *(const s16x8*)&As[(wm * 64 + mt * 16 + l15) * 32 + quad * 8];
#pragma unroll
    for (int nt = 0; nt < 2; ++nt)
      bf[nt] = *(const s16x8*)&Bs[(wn * 32 + nt * 16 + l15) * 32 + quad * 8];
#pragma unroll
    for (int mt = 0; mt < 4; ++mt)
#pragma unroll
      for (int nt = 0; nt < 2; ++nt)
        acc[mt][nt] = MFMA16(af[mt], bf[nt], acc[mt][nt]);
  }

#pragma unroll
  for (int mt = 0; mt < 4; ++mt)
#pragma unroll
    for (int r = 0; r < 4; ++r) {
      const int i = i0 + wm * 64 + mt * 16 + quad * 4 + r;
#pragma unroll
      for (int nt = 0; nt < 2; ++nt) {
        const int j = j0 + wn * 32 + nt * 16 + l15;
        out[(size_t)i * DIMD + j] = acc[mt][nt][r] + bp[j];
      }
    }
}

// ---------------------------------------------------------------------------
extern "C" void kernel_launch(void* const* d_in, const int* in_sizes, int n_in,
                              void* d_out, int out_size, void* d_ws, size_t ws_size,
                              hipStream_t stream) {
  (void)in_sizes; (void)n_in; (void)out_size; (void)ws_size;
  const float* x    = (const float*)d_in[0];
  const float* Wqkv = (const float*)d_in[1];
  const float* bqkv = (const float*)d_in[2];
  const float* Aq   = (const float*)d_in[3];
  const float* Bq   = (const float*)d_in[4];
  const float* Av   = (const float*)d_in[5];
  const float* Bv   = (const float*)d_in[6];
  const float* relh = (const float*)d_in[7];
  const float* relw = (const float*)d_in[8];
  const float* Wp   = (const float*)d_in[9];
  const float* bp   = (const float*)d_in[10];
  float* out = (float*)d_out;

  float* ws = (float*)d_ws;
  short* xe    = (short*)(ws);
  short* we    = (short*)(ws + 1638400);
  short* wpb   = (short*)(ws + 2560000);
  short* qkvb  = (short*)(ws + 2854912);
  short* vtb   = (short*)(ws + 7573504);
  short* attnb = (short*)(ws + 9146368);

  k_prep_w<<<dim3(3072), dim3(64), 0, stream>>>(Wqkv, Bq, Bv, Wp, we, wpb);
  k_prep_x<<<dim3(NTOK), dim3(64), 0, stream>>>(x, Aq, Av, xe);
  k_qkv<<<dim3(18, 32), dim3(256), 0, stream>>>(xe, we, bqkv, qkvb, vtb);
  k_attn7<<<dim3(64, 12), dim3(512), 0, stream>>>(qkvb, vtb, relh, relw, attnb);
  k_proj<<<dim3(12, 32), dim3(256), 0, stream>>>(attnb, wpb, bp, out);
}

// Round 9
// 215.533 us; speedup vs baseline: 2.6815x; 2.6815x over previous
//
#include <hip/hip_runtime.h>

// x:(1,64,64,768) -> n=4096 tokens, DIM=768, 12 heads x 64 dim
#define NTOK 4096
#define DIMD 768
#define NHD  12
#define HDD  64
#define DK   800   // extended K: 768 x | 4 lora-q | 4 lora-v | 24 zero

typedef float  f32x2  __attribute__((ext_vector_type(2)));
typedef float  f32x4  __attribute__((ext_vector_type(4)));
typedef float  f32x16 __attribute__((ext_vector_type(16)));
typedef short  s16x8  __attribute__((ext_vector_type(8)));

#define MFMA16(a, b, c) __builtin_amdgcn_mfma_f32_16x16x32_bf16(a, b, c, 0, 0, 0)
#define MFMA32(a, b, c) __builtin_amdgcn_mfma_f32_32x32x16_bf16(a, b, c, 0, 0, 0)

#if __has_builtin(__builtin_amdgcn_exp2f)
#define EXP2(x) __builtin_amdgcn_exp2f(x)
#else
#define EXP2(x) exp2f(x)
#endif

__device__ inline short f2b(float f) {  // fp32 -> bf16 RNE
  unsigned u = __float_as_uint(f);
  u += 0x7FFFu + ((u >> 16) & 1u);
  return (short)(u >> 16);
}
__device__ inline float b2f(short s) {
  return __uint_as_float(((unsigned)(unsigned short)s) << 16);
}
__device__ inline void gl_lds16(const short* g, short* l) {
  __builtin_amdgcn_global_load_lds(
      (const __attribute__((address_space(1))) unsigned int*)g,
      (__attribute__((address_space(3))) unsigned int*)l, 16, 0, 0);
}

// ws layout (float units):
//   xe    @0         bf16 [4096][800]
//   we    @1638400   bf16 [2304][800]
//   wpb   @2560000   bf16 [768][768]
//   qkvb  @2854912   bf16 [3][12][4096][64]  (V third unused)
//   vtb   @7573504   bf16 [12][64][4096]  (keys pi-permuted within 16-groups)
//   attnb @9146368   bf16 [4096][768]

// ---------------------------------------------------------------------------
// Kernel A+B fused: blocks [0,3072) build we/wpb; blocks [3072,7168) build
// xe[4096][800] = [bf16(x) | 0.25*x@Aq^T | 0.25*x@Av^T | 0]. Independent
// work items, fused to remove one launch gap from the serial chain.
__global__ __launch_bounds__(64)
void k_prep(const float* __restrict__ Wqkv, const float* __restrict__ Bq,
            const float* __restrict__ Bv, const float* __restrict__ Wp,
            short* __restrict__ we, short* __restrict__ wpb,
            const float* __restrict__ x, const float* __restrict__ Aq,
            const float* __restrict__ Av, short* __restrict__ xe) {
  const int bid = blockIdx.x;
  const int l = threadIdx.x;
  if (bid < 3072) {
    const int j = bid;
    if (j < 2304) {
#pragma unroll
      for (int k = 0; k < 12; ++k)
        we[(size_t)j * DK + l + 64 * k] =
            f2b(Wqkv[(size_t)j * DIMD + l + 64 * k]);
      if (l < 32) {
        int c = 768 + l;
        short v = 0;
        if (l < 4) {
          if (j < 768) v = f2b(Bq[j * 4 + l]);
        } else if (l < 8) {
          if (j >= 1536) v = f2b(Bv[(j - 1536) * 4 + (l - 4)]);
        }
        we[(size_t)j * DK + c] = v;
      }
    } else {
      const int jr = j - 2304;
#pragma unroll
      for (int k = 0; k < 12; ++k)
        wpb[(size_t)jr * DIMD + l + 64 * k] =
            f2b(Wp[(size_t)jr * DIMD + l + 64 * k]);
    }
  } else {
    const int i = bid - 3072;
    float xv[12];
#pragma unroll
    for (int k = 0; k < 12; ++k) xv[k] = x[(size_t)i * DIMD + l + 64 * k];
#pragma unroll
    for (int k = 0; k < 12; ++k)
      xe[(size_t)i * DK + l + 64 * k] = f2b(xv[k]);
    float a8[8];
#pragma unroll
    for (int o = 0; o < 8; ++o) {
      const float* A = (o < 4) ? (Aq + o * DIMD) : (Av + (o - 4) * DIMD);
      float acc = 0.f;
#pragma unroll
      for (int k = 0; k < 12; ++k) acc = fmaf(xv[k], A[l + 64 * k], acc);
#pragma unroll
      for (int off = 32; off; off >>= 1) acc += __shfl_xor(acc, off, 64);
      a8[o] = acc;
    }
    if (l < 32) {
      float v = 0.f;
#pragma unroll
      for (int o = 0; o < 8; ++o)
        if (l == o) v = 0.25f * a8[o];
      xe[(size_t)i * DK + 768 + l] = (l < 8) ? f2b(v) : (short)0;
    }
  }
}

// ---------------------------------------------------------------------------
// Kernel 2: bf16 MFMA qkv GEMM over extended K=800 (LoRA folded in).
// BK=64 main loop (12 steps) + BK=32 tail, XOR-swizzled LDS, Cs aliased over
// As/Bs (33.3 KB LDS), XCD-aware swizzle. (unchanged from R5)
__global__ __launch_bounds__(256)
void k_qkv(const short* __restrict__ xe, const short* __restrict__ we,
           const float* __restrict__ bqkv, short* __restrict__ qkvb,
           short* __restrict__ vtb) {
  const int d_ = blockIdx.y * 18 + blockIdx.x;
  const int lin = (d_ & 7) * 72 + (d_ >> 3);
  const int j0 = (lin % 18) * 128;
  const int i0 = (lin / 18) * 128;

  __shared__ __align__(16) short shm[16640];
  short* As = shm;
  short* Bs = shm + 8192;
  short* Cs = shm;

  const int t = threadIdx.x, lane = t & 63, w = t >> 6;
  const int l15 = lane & 15, quad = lane >> 4;
  const int wm = w >> 1, wn = w & 1;

  f32x4 acc[4][4];
#pragma unroll
  for (int a = 0; a < 4; ++a)
#pragma unroll
    for (int b = 0; b < 4; ++b) acc[a][b] = (f32x4){0.f, 0.f, 0.f, 0.f};

  for (int kk = 0; kk < 768; kk += 64) {
    __syncthreads();
#pragma unroll
    for (int rep = 0; rep < 4; ++rep) {
      int c = rep * 256 + w * 64 + lane;
      int row = c >> 3, u = (c & 7) ^ (row & 7);
      gl_lds16(xe + (size_t)(i0 + row) * DK + kk + u * 8,
               &As[(rep * 256 + w * 64) * 8]);
      gl_lds16(we + (size_t)(j0 + row) * DK + kk + u * 8,
               &Bs[(rep * 256 + w * 64) * 8]);
    }
    __syncthreads();
#pragma unroll
    for (int kh2 = 0; kh2 < 2; ++kh2) {
      s16x8 af[4], bf[4];
#pragma unroll
      for (int mt = 0; mt < 4; ++mt) {
        int row = wm * 64 + mt * 16 + l15;
        af[mt] = *(const s16x8*)&As[row * 64 +
                                    (((kh2 * 4 + quad) ^ (l15 & 7)) * 8)];
      }
#pragma unroll
      for (int nt = 0; nt < 4; ++nt) {
        int row = wn * 64 + nt * 16 + l15;
        bf[nt] = *(const s16x8*)&Bs[row * 64 +
                                    (((kh2 * 4 + quad) ^ (l15 & 7)) * 8)];
      }
#pragma unroll
      for (int mt = 0; mt < 4; ++mt)
#pragma unroll
        for (int nt = 0; nt < 4; ++nt)
          acc[mt][nt] = MFMA16(af[mt], bf[nt], acc[mt][nt]);
    }
  }

  __syncthreads();
#pragma unroll
  for (int rep = 0; rep < 2; ++rep) {
    int c = rep * 256 + w * 64 + lane;
    gl_lds16(xe + (size_t)(i0 + (c >> 2)) * DK + 768 + (c & 3) * 8,
             &As[(rep * 256 + w * 64) * 8]);
    gl_lds16(we + (size_t)(j0 + (c >> 2)) * DK + 768 + (c & 3) * 8,
             &Bs[(rep * 256 + w * 64) * 8]);
  }
  __syncthreads();
  {
    s16x8 af[4], bf[4];
#pragma unroll
    for (int mt = 0; mt < 4; ++mt)
      af[mt] = *(const s16x8*)&As[(wm * 64 + mt * 16 + l15) * 32 + quad * 8];
#pragma unroll
    for (int nt = 0; nt < 4; ++nt)
      bf[nt] = *(const s16x8*)&Bs[(wn * 64 + nt * 16 + l15) * 32 + quad * 8];
#pragma unroll
    for (int mt = 0; mt < 4; ++mt)
#pragma unroll
      for (int nt = 0; nt < 4; ++nt)
        acc[mt][nt] = MFMA16(af[mt], bf[nt], acc[mt][nt]);
  }
  __syncthreads();

  const int which = j0 / DIMD;
  float bj[4];
#pragma unroll
  for (int nt = 0; nt < 4; ++nt) bj[nt] = bqkv[j0 + wn * 64 + nt * 16 + l15];

#pragma unroll
  for (int mt = 0; mt < 4; ++mt)
#pragma unroll
    for (int r = 0; r < 4; ++r) {
      const int row = wm * 64 + mt * 16 + quad * 4 + r;
#pragma unroll
      for (int nt = 0; nt < 4; ++nt) {
        const int col = wn * 64 + nt * 16 + l15;
        Cs[row * 130 + col] = f2b(acc[mt][nt][r] + bj[nt]);
      }
    }
  __syncthreads();
  const int base_head = (j0 - which * DIMD) >> 6;
  if (which != 2) {
#pragma unroll
    for (int rp = 0; rp < 8; ++rp) {
      int f = t + 256 * rp;
      int row = f >> 4, ch = f & 15;
      int head = base_head + (ch >> 3);
      int ddb = (ch & 7) * 8;
      s16x8 v = *(const s16x8*)&Cs[row * 130 + ch * 8];
      *(s16x8*)&qkvb[(((size_t)which * NHD + head) * NTOK + i0 + row) * HDD + ddb] = v;
    }
  } else {
#pragma unroll
    for (int rp = 0; rp < 8; ++rp) {
      int f = t + 256 * rp;
      int dcol = f >> 4, n8 = (f & 15) * 8;
      unsigned wds[4];
#pragma unroll
      for (int m = 0; m < 4; ++m) {
        int s0 = n8 + 2 * m, s1 = s0 + 1;
        int sr0 = (s0 & 0x70) | ((((s0 >> 2) & 3) == 1 ? 2 : ((s0 >> 2) & 3) == 2 ? 1 : ((s0 >> 2) & 3)) << 2) | (s0 & 3);
        int sr1 = (s1 & 0x70) | ((((s1 >> 2) & 3) == 1 ? 2 : ((s1 >> 2) & 3) == 2 ? 1 : ((s1 >> 2) & 3)) << 2) | (s1 & 3);
        unsigned lo = (unsigned short)Cs[sr0 * 130 + dcol];
        unsigned hi = (unsigned short)Cs[sr1 * 130 + dcol];
        wds[m] = lo | (hi << 16);
      }
      short* dst = vtb + ((size_t)(base_head * 64) + dcol) * NTOK + i0 + n8;
      *(int4*)dst = *(int4*)&wds[0];
    }
  }
}

// ---------------------------------------------------------------------------
// Kernel 4: 32x32x16-MFMA flash attention, swapped operands (S^T / O^T).
// KVBLK=128, counted-vmcnt, raw barriers + lgkmcnt fences, split DMA issue.
// (R5 structure verbatim -- session-best 222.09 us total / ~102 us attn.)
// LDS shorts: KB0@0, KB1@4096, VB0@8192, VB1@12288, bHb@16384..20480.
__global__ __launch_bounds__(256)
void k_attn7(const short* __restrict__ qkvb, const short* __restrict__ vtb,
             const float* __restrict__ relh, const float* __restrict__ relw,
             short* __restrict__ attnb) {
  // T1: bijective XCD swizzle (768 = 8 XCDs x 96).
  const int d_ = blockIdx.y * 64 + blockIdx.x;      // dispatch-linear (x fastest)
  const int lin = (d_ & 7) * 96 + (d_ >> 3);        // bijective (768 % 8 == 0)
  const int head = lin >> 6;
  const int hq = lin & 63;
  const int n0 = hq * 64;

  __shared__ short sm[20480];
  short* smb = sm;

  const short* qg  = qkvb + (size_t)(0 * NHD + head) * NTOK * HDD;
  const short* kg  = qkvb + (size_t)(1 * NHD + head) * NTOK * HDD;
  const short* vtg = vtb + (size_t)head * HDD * NTOK;

  const int t = threadIdx.x;
  const int w = t >> 6, lane = t & 63;
  const int l31 = lane & 31, h = lane >> 5;
  const int kh = w >> 1, qh = w & 1;
  const int q = qh * 32 + l31;

  // DMA source: wave w stages chunk-pair s=w of each 32-row half-tile.
  const int rowp = lane >> 1;
  const int cw = (w * 2 + (lane & 1)) * 8;
  const short* gK0 = kg + (size_t)rowp * HDD + cw;
  const short* gK1 = gK0 + 32 * HDD;
  const short* gV0 = vtg + (size_t)rowp * NTOK + cw;
  const short* gV1 = gV0 + (size_t)32 * NTOK;

  // Q B-fragments (persist)
  s16x8 qb[4];
#pragma unroll
  for (int s = 0; s < 4; ++s)
    qb[s] = *(const s16x8*)&qg[(size_t)(n0 + q) * HDD + s * 16 + 8 * h];

  // ---- prologue: RW -> overlay ----
#pragma unroll
  for (int rp = 0; rp < 4; ++rp) {
    int f = t + 256 * rp;
    int d = f >> 3, c = (f & 7) * 8;
    float4 v0 = make_float4(0, 0, 0, 0), v1 = v0;
    if (d < 127) {
      const float* s_ = relw + (size_t)d * HDD + c;
      v0 = *(const float4*)s_; v1 = *(const float4*)(s_ + 4);
    }
    short4 b0, b1;
    b0.x = f2b(v0.x); b0.y = f2b(v0.y); b0.z = f2b(v0.z); b0.w = f2b(v0.w);
    b1.x = f2b(v1.x); b1.y = f2b(v1.y); b1.z = f2b(v1.z); b1.w = f2b(v1.w);
    *(short4*)&smb[d * 72 + c] = b0;
    *(short4*)&smb[d * 72 + c + 4] = b1;
  }
  __syncthreads();

  // M^T = RW @ Q^T (log2e folded at store)
  f32x16 mc0 = (f32x16)(0.f), mc1 = (f32x16)(0.f);
#pragma unroll
  for (int s = 0; s < 4; ++s) {
    s16x8 a0 = *(const s16x8*)&smb[((kh * 2) * 32 + l31) * 72 + s * 16 + 8 * h];
    s16x8 a1 = *(const s16x8*)&smb[((kh * 2 + 1) * 32 + l31) * 72 + s * 16 + 8 * h];
    mc0 = MFMA32(a0, qb[s], mc0);
    mc1 = MFMA32(a1, qb[s], mc1);
  }
  __syncthreads();
#pragma unroll
  for (int reg = 0; reg < 16; ++reg) {
    int dl = (reg & 3) + 8 * (reg >> 2) + 4 * h;
    smb[(kh * 64 + dl) * 64 + q] = f2b(mc0[reg] * 1.44269504f);
    smb[(kh * 64 + 32 + dl) * 64 + q] = f2b(mc1[reg] * 1.44269504f);
  }
  __syncthreads();

  f32x2 bw2[8];
#pragma unroll
  for (int i = 0; i < 8; ++i)
#pragma unroll
    for (int p = 0; p < 2; ++p) {
      int reg = 2 * i + p;
      int kl64 = kh * 32 + (reg & 3) + 8 * (reg >> 2) + 4 * h;
      int dneed = q - kl64 + 63;  // [0,126]
      bw2[i][p] = b2f(smb[dneed * 64 + q]);
    }
  __syncthreads();

  // RH -> overlay
#pragma unroll
  for (int rp = 0; rp < 2; ++rp) {
    int f = t + 256 * rp;
    int kt = f >> 3, c = (f & 7) * 8;
    const float* s_ = relh + (size_t)(hq + 63 - kt) * HDD + c;
    float4 v0 = *(const float4*)s_, v1 = *(const float4*)(s_ + 4);
    short4 b0, b1;
    b0.x = f2b(v0.x); b0.y = f2b(v0.y); b0.z = f2b(v0.z); b0.w = f2b(v0.w);
    b1.x = f2b(v1.x); b1.y = f2b(v1.y); b1.z = f2b(v1.z); b1.w = f2b(v1.w);
    *(short4*)&smb[kt * 72 + c] = b0;
    *(short4*)&smb[kt * 72 + c + 4] = b1;
  }
  __syncthreads();

  // bH^T = RH @ Q^T -> bHb @16384 (log2e prefolded)
  f32x16 hc = (f32x16)(0.f);
#pragma unroll
  for (int s = 0; s < 4; ++s) {
    s16x8 a = *(const s16x8*)&smb[(kh * 32 + l31) * 72 + s * 16 + 8 * h];
    hc = MFMA32(a, qb[s], hc);
  }
#pragma unroll
  for (int reg = 0; reg < 16; ++reg) {
    int ktl = kh * 32 + (reg & 3) + 8 * (reg >> 2) + 4 * h;
    smb[16384 + ktl * 64 + q] = f2b(hc[reg] * 1.44269504f);
  }
  __syncthreads();  // RH reads done; bHb published; DMA may write [0,16384)

  // bootstrap: subs 0,1 -> KB0,KB1,VB0,VB1 (queue: [K(4), V(4)])
  gl_lds16(gK0, smb + 0 + w * 512);
  gl_lds16(gK1, smb + 2048 + w * 512);
  gl_lds16(gK0 + 4096, smb + 4096 + w * 512);
  gl_lds16(gK1 + 4096, smb + 4096 + 2048 + w * 512);
  gK0 += 8192; gK1 += 8192;
  gl_lds16(gV0, smb + 8192 + w * 512);
  gl_lds16(gV1, smb + 8192 + 2048 + w * 512);
  gl_lds16(gV0 + 64, smb + 12288 + w * 512);
  gl_lds16(gV1 + 64, smb + 12288 + 2048 + w * 512);
  gV0 += 128; gV1 += 128;

  // Fragment read bases: [half][s][row][h] layout -> contiguous wave reads.
  int baseS[4], baseV[2];
#pragma unroll
  for (int s = 0; s < 4; ++s)
    baseS[s] = kh * 2048 + s * 512 + l31 * 16 + h * 8;
#pragma unroll
  for (int s2 = 0; s2 < 2; ++s2)
    baseV[s2] = (kh * 2 + s2) * 512 + l31 * 16 + h * 8;

  f32x2 ps2 = (f32x2)(0.f);
  f32x16 oc0 = (f32x16)(0.f), oc1 = (f32x16)(0.f);

#define SM_BLOCK(SC, BHL, PK)                                                  \
    _Pragma("unroll") for (int i = 0; i < 8; ++i) {                            \
      f32x2 s2;                                                                \
      s2[0] = (SC)[2 * i]; s2[1] = (SC)[2 * i + 1];                            \
      f32x2 r = s2 * 0.18033688f + (bw2[i] + (BHL));                           \
      float e0 = EXP2(r[0]);                                                   \
      float e1 = EXP2(r[1]);                                                   \
      f32x2 e2; e2[0] = e0; e2[1] = e1;                                        \
      ps2 += e2;                                                               \
      PK[i] = __builtin_amdgcn_perm(__float_as_uint(e1),                       \
                                    __float_as_uint(e0), 0x07060302u);         \
    }

#define PV_BLOCK(VOFF, PK)                                                     \
    _Pragma("unroll") for (int s2i = 0; s2i < 2; ++s2i) {                      \
      union { unsigned u[4]; s16x8 v; } B;                                     \
      B.u[0] = PK[4 * s2i + 0]; B.u[1] = PK[4 * s2i + 1];                      \
      B.u[2] = PK[4 * s2i + 2]; B.u[3] = PK[4 * s2i + 3];                      \
      s16x8 a0 = *(const s16x8*)&smb[(VOFF) + baseV[s2i]];                     \
      s16x8 a1 = *(const s16x8*)&smb[(VOFF) + 2048 + baseV[s2i]];              \
      oc0 = MFMA32(a0, B.v, oc0);                                              \
      oc1 = MFMA32(a1, B.v, oc1);                                              \
    }

#define ITER2(KTa, PF)                                                         \
  {                                                                            \
    asm volatile("s_waitcnt vmcnt(4)" ::: "memory");                           \
    __builtin_amdgcn_s_barrier();                                              \
    __builtin_amdgcn_sched_barrier(0);                                         \
    f32x16 sa = (f32x16)(0.f), sb = (f32x16)(0.f);                             \
    _Pragma("unroll") for (int s = 0; s < 4; ++s) {                            \
      s16x8 ka = *(const s16x8*)&smb[0 + baseS[s]];                            \
      sa = MFMA32(ka, qb[s], sa);                                              \
    }                                                                          \
    _Pragma("unroll") for (int s = 0; s < 4; ++s) {                            \
      s16x8 kb = *(const s16x8*)&smb[4096 + baseS[s]];                         \
      sb = MFMA32(kb, qb[s], sb);                                              \
    }                                                                          \
    float bhla = b2f(smb[16384 + (KTa) * 64 + q]);                             \
    float bhlb = b2f(smb[16384 + (KTa) * 64 + 64 + q]);                        \
    asm volatile("s_waitcnt lgkmcnt(0) vmcnt(0)" ::: "memory");                \
    __builtin_amdgcn_sched_barrier(0);                                         \
    __builtin_amdgcn_s_barrier();                                              \
    __builtin_amdgcn_sched_barrier(0);                                         \
    if (PF) {                                                                  \
      gl_lds16(gK0, smb + 0 + w * 512);                                        \
      gl_lds16(gK1, smb + 2048 + w * 512);                                     \
      gl_lds16(gK0 + 4096, smb + 4096 + w * 512);                              \
      gl_lds16(gK1 + 4096, smb + 4096 + 2048 + w * 512);                       \
      gK0 += 8192; gK1 += 8192;                                                \
    }                                                                          \
    unsigned pkA[8], pkB[8];                                                   \
    SM_BLOCK(sa, bhla, pkA);                                                   \
    PV_BLOCK(8192, pkA);                                                       \
    SM_BLOCK(sb, bhlb, pkB);                                                   \
    PV_BLOCK(12288, pkB);                                                      \
    if (PF) {                                                                  \
      asm volatile("s_waitcnt lgkmcnt(0)" ::: "memory");                       \
      __builtin_amdgcn_sched_barrier(0);                                       \
      __builtin_amdgcn_s_barrier();                                            \
      __builtin_amdgcn_sched_barrier(0);                                       \
      gl_lds16(gV0, smb + 8192 + w * 512);                                     \
      gl_lds16(gV1, smb + 8192 + 2048 + w * 512);                              \
      gl_lds16(gV0 + 64, smb + 12288 + w * 512);                               \
      gl_lds16(gV1 + 64, smb + 12288 + 2048 + w * 512);                        \
      gV0 += 128; gV1 += 128;                                                  \
    }                                                                          \
  }

  for (int t2 = 0; t2 < 31; ++t2) {
    ITER2(2 * t2, 1);
  }
  ITER2(62, 0);
#undef ITER2
#undef SM_BLOCK
#undef PV_BLOCK

  // ---- epilogue: combine kh halves, normalize, transpose, store ----
  __syncthreads();
  float ps = ps2[0] + ps2[1];
  float* obuf = (float*)smb;          // [64][66] floats @0
  float* psb  = (float*)smb + 4224;
  short* tbuf = smb + 8576;           // [64][66] shorts
  ps += __shfl_xor(ps, 32, 64);
  if (kh == 1) {
#pragma unroll
    for (int reg = 0; reg < 16; ++reg) {
      int dl = (reg & 3) + 8 * (reg >> 2) + 4 * h;
      obuf[dl * 66 + q] = oc0[reg];
      obuf[(32 + dl) * 66 + q] = oc1[reg];
    }
    if (lane < 32) psb[q] = ps;
  }
  __syncthreads();
  if (kh == 0) {
    float inv = 1.f / (ps + psb[q]);
#pragma unroll
    for (int reg = 0; reg < 16; ++reg) {
      int dl = (reg & 3) + 8 * (reg >> 2) + 4 * h;
      tbuf[dl * 66 + q] = f2b((oc0[reg] + obuf[dl * 66 + q]) * inv);
      tbuf[(32 + dl) * 66 + q] = f2b((oc1[reg] + obuf[(32 + dl) * 66 + q]) * inv);
    }
  }
  __syncthreads();
  {
    int qq = t >> 2, seg = t & 3;
    unsigned wds[8];
#pragma unroll
    for (int m = 0; m < 8; ++m) {
      unsigned lo = (unsigned short)tbuf[(seg * 16 + 2 * m) * 66 + qq];
      unsigned hi = (unsigned short)tbuf[(seg * 16 + 2 * m + 1) * 66 + qq];
      wds[m] = lo | (hi << 16);
    }
    short* dst = attnb + (size_t)(n0 + qq) * DIMD + head * 64 + seg * 16;
    *(int4*)dst = *(int4*)&wds[0];
    *(int4*)(dst + 8) = *(int4*)&wds[4];
  }
}

// ---------------------------------------------------------------------------
// Kernel 5: bf16 MFMA proj: out = attn @ Wp^T + bp (fp32 out)
__global__ __launch_bounds__(256)
void k_proj(const short* __restrict__ ab, const short* __restrict__ wpb,
            const float* __restrict__ bp, float* __restrict__ out) {
  const int d_ = blockIdx.y * 12 + blockIdx.x;
  const int lin = (d_ & 7) * 48 + (d_ >> 3);
  const int j0 = (lin % 12) * 64;
  const int i0 = (lin / 12) * 128;
  __shared__ short As[128 * 32];
  __shared__ short Bs[64 * 32];
  const int t = threadIdx.x, lane = t & 63, w = t >> 6;
  const int l15 = lane & 15, quad = lane >> 4;
  const int wm = w >> 1, wn = w & 1;

  f32x4 acc[4][2];
#pragma unroll
  for (int a = 0; a < 4; ++a)
#pragma unroll
    for (int b = 0; b < 2; ++b) acc[a][b] = (f32x4){0.f, 0.f, 0.f, 0.f};

  for (int kk = 0; kk < DIMD; kk += 32) {
    __syncthreads();
#pragma unroll
    for (int rep = 0; rep < 2; ++rep) {
      int c = rep * 256 + w * 64 + lane;
      gl_lds16(ab + (size_t)(i0 + (c >> 2)) * DIMD + kk + (c & 3) * 8,
               &As[(rep * 256 + w * 64) * 8]);
    }
    {
      gl_lds16(wpb + (size_t)(j0 + ((w * 64 + lane) >> 2)) * DIMD + kk +
                   ((w * 64 + lane) & 3) * 8,
               &Bs[(w * 64) * 8]);
    }
    __syncthreads();
    s16x8 af[4], bf[2];
#pragma unroll
    for (int mt = 0; mt < 4; ++mt)
      af[mt] = *(const s16x8*)&As[(wm * 64 + mt * 16 + l15) * 32 + quad * 8];
#pragma unroll
    for (int nt = 0; nt < 2; ++nt)
      bf[nt] = *(const s16x8*)&Bs[(wn * 32 + nt * 16 + l15) * 32 + quad * 8];
#pragma unroll
    for (int mt = 0; mt < 4; ++mt)
#pragma unroll
      for (int nt = 0; nt < 2; ++nt)
        acc[mt][nt] = MFMA16(af[mt], bf[nt], acc[mt][nt]);
  }

#pragma unroll
  for (int mt = 0; mt < 4; ++mt)
#pragma unroll
    for (int r = 0; r < 4; ++r) {
      const int i = i0 + wm * 64 + mt * 16 + quad * 4 + r;
#pragma unroll
      for (int nt = 0; nt < 2; ++nt) {
        const int j = j0 + wn * 32 + nt * 16 + l15;
        out[(size_t)i * DIMD + j] = acc[mt][nt][r] + bp[j];
      }
    }
}

// ---------------------------------------------------------------------------
extern "C" void kernel_launch(void* const* d_in, const int* in_sizes, int n_in,
                              void* d_out, int out_size, void* d_ws, size_t ws_size,
                              hipStream_t stream) {
  (void)in_sizes; (void)n_in; (void)out_size; (void)ws_size;
  const float* x    = (const float*)d_in[0];
  const float* Wqkv = (const float*)d_in[1];
  const float* bqkv = (const float*)d_in[2];
  const float* Aq   = (const float*)d_in[3];
  const float* Bq   = (const float*)d_in[4];
  const float* Av   = (const float*)d_in[5];
  const float* Bv   = (const float*)d_in[6];
  const float* relh = (const float*)d_in[7];
  const float* relw = (const float*)d_in[8];
  const float* Wp   = (const float*)d_in[9];
  const float* bp   = (const float*)d_in[10];
  float* out = (float*)d_out;

  float* ws = (float*)d_ws;
  short* xe    = (short*)(ws);
  short* we    = (short*)(ws + 1638400);
  short* wpb   = (short*)(ws + 2560000);
  short* qkvb  = (short*)(ws + 2854912);
  short* vtb   = (short*)(ws + 7573504);
  short* attnb = (short*)(ws + 9146368);

  k_prep<<<dim3(7168), dim3(64), 0, stream>>>(Wqkv, Bq, Bv, Wp, we, wpb,
                                              x, Aq, Av, xe);
  k_qkv<<<dim3(18, 32), dim3(256), 0, stream>>>(xe, we, bqkv, qkvb, vtb);
  k_attn7<<<dim3(64, NHD), dim3(256), 0, stream>>>(qkvb, vtb, relh, relw, attnb);
  k_proj<<<dim3(12, 32), dim3(256), 0, stream>>>(attnb, wpb, bp, out);
}